// Round 5
// baseline (3455.331 us; speedup 1.0000x reference)
//
#include <hip/hip_runtime.h>
#include <hip/hip_bf16.h>
#include <math.h>

#define T_   64
#define B_   2048
#define OBS_ 48
#define H_   256
#define M1_  512
#define M2_  256
#define A_   12
#define BH_  (B_ * H_)
#define KP_  320   // padded K for scan: 64 (x, padded from 48) + 256 (h)

typedef unsigned short u16;
typedef __attribute__((ext_vector_type(8))) short bf16x8;
typedef __attribute__((ext_vector_type(4))) float f32x4;

static __device__ __forceinline__ u16 f2b(float f) {
    __hip_bfloat16 h = __float2bfloat16(f);
    return *reinterpret_cast<u16*>(&h);
}
static __device__ __forceinline__ float b2f(u16 u) {
    union { unsigned u32; float f; } v; v.u32 = ((unsigned)u) << 16; return v.f;
}
static __device__ __forceinline__ float sigm(float x) {
    return 1.0f / (1.0f + __expf(-x));
}
static __device__ __forceinline__ float tanh_fast(float x) {
    x = fminf(fmaxf(x, -15.0f), 15.0f);
    float e = __expf(2.0f * x);
    return (e - 1.0f) / (e + 1.0f);
}
static __device__ __forceinline__ float elu(float x) {
    return x > 0.0f ? x : (__expf(x) - 1.0f);
}

// ---------------------------------------------------------------------------
// Pre-pass kernels
// ---------------------------------------------------------------------------
__global__ void prep_xpad(const float* __restrict__ x, u16* __restrict__ xpad) {
    const int i = blockIdx.x * 256 + threadIdx.x;   // over T*B*64
    const int r = i >> 6, k = i & 63;
    xpad[i] = (k < OBS_) ? f2b(x[r * OBS_ + k]) : (u16)0;
}

__global__ void prep_wcat(const float* __restrict__ W_ih, const float* __restrict__ W_hh,
                          u16* __restrict__ Wcat) {
    const int n = blockIdx.x;        // 1024
    const int k = threadIdx.x;       // 320
    float v;
    if (k < OBS_)      v = W_ih[n * OBS_ + k];
    else if (k < 64)   v = 0.0f;
    else               v = W_hh[n * H_ + (k - 64)];
    Wcat[n * KP_ + k] = f2b(v);
}

__global__ void prep_w1t(const float* __restrict__ W1, u16* __restrict__ W1T) {
    W1T[blockIdx.x * 256 + threadIdx.x] = f2b(W1[threadIdx.x * M1_ + blockIdx.x]);
}

__global__ void prep_w2t(const float* __restrict__ W2, u16* __restrict__ W2T) {
    W2T[blockIdx.x * 512 + threadIdx.x] = f2b(W2[threadIdx.x * M2_ + blockIdx.x]);
}

__global__ void prep_wht(const float* __restrict__ Wm, const float* __restrict__ Ws,
                         u16* __restrict__ WhT) {
    const int n = blockIdx.x, k = threadIdx.x;
    float v = 0.0f;
    if (n < 12)                 v = Wm[k * A_ + n];
    else if (n >= 16 && n < 28) v = Ws[k * A_ + (n - 16)];
    WhT[n * 256 + k] = f2b(v);
}

// ---------------------------------------------------------------------------
// Persistent row-partitioned LSTM scan. ONE dispatch, 64 blocks x 512 thr.
// Block owns batch rows b0..b0+31 for ALL 64 timesteps and ALL 1024 gate
// columns -> NO inter-block dependency (h_{t+1}[b] depends only on h_t[b]).
// - 8 waves = m-frag(2: 16 rows) x col-group(4: 64 h-cols). Each wave computes
//   its cols for all 4 gates -> gate fusion entirely in registers.
// - c state: 16 fp32 regs/lane, never touches memory after init.
// - h: 32x320 bf16 LDS tile (XOR-swizzled 16B chunks), rewritten each step.
// - Wcat streamed from L2 every step (640 KB/block), ring-4 B prefetch.
// - 2 barriers/step; x(t+1)/done(t+1) prefetched during compute.
// ---------------------------------------------------------------------------
#define SW32(row, chunk) ((size_t)(row) * 320 + (size_t)(((chunk) ^ ((row) & 7)) << 3))

__global__ __launch_bounds__(512, 2) void lstm_scan_rows(
    const u16*  __restrict__ xpad,   // [T][B][64]
    const int*  __restrict__ done,   // [T][B]
    u16*        __restrict__ hs_out, // [T][B][256]  (hs_out[t] = h after step t)
    const float* __restrict__ h0,    // [B][256]
    const float* __restrict__ c0,    // [B][256]
    const u16*  __restrict__ Wcat,   // [1024][320]
    const float* __restrict__ b_ih,
    const float* __restrict__ b_hh)
{
    __shared__ u16   a_sm[32 * 320];   // 20 KB
    __shared__ float keep2[2][32];

    const int tid  = threadIdx.x;
    const int lane = tid & 63;
    const int wave = tid >> 6;        // 0..7
    const int mf   = wave & 1;        // 16-row m-frag
    const int jg   = wave >> 1;       // 0..3: h-cols [jg*64, jg*64+64)
    const int quad = lane >> 4, l16 = lane & 15;
    const int b0 = blockIdx.x * 32;

    // ---- bias preload: [jc][gate] for col jg*64+jc*16+l16 ----
    float bias[4][4];
    #pragma unroll
    for (int jc = 0; jc < 4; ++jc) {
        const int col = jg * 64 + jc * 16 + l16;
        #pragma unroll
        for (int g = 0; g < 4; ++g)
            bias[jc][g] = b_ih[g * 256 + col] + b_hh[g * 256 + col];
    }

    // ---- persistent c state: [jc][r], row = mf*16+quad*4+r ----
    float c_reg[4][4];
    #pragma unroll
    for (int jc = 0; jc < 4; ++jc)
        #pragma unroll
        for (int r = 0; r < 4; ++r)
            c_reg[jc][r] = c0[(size_t)(b0 + mf * 16 + quad * 4 + r) * H_
                              + jg * 64 + jc * 16 + l16];

    // ---- stage x_0 (chunks 0..7) and h_0 (chunks 8..39) ----
    if (tid < 256) {
        const int row = tid >> 3, ch = tid & 7;
        *(uint4*)(a_sm + SW32(row, ch)) =
            *(const uint4*)(xpad + (size_t)(b0 + row) * 64 + ch * 8);
    }
    {
        const int row = tid >> 4, seg = tid & 15;   // 16 cols per seg
        const float* hp = h0 + (size_t)(b0 + row) * H_ + seg * 16;
        u16 tmp[16];
        #pragma unroll
        for (int i = 0; i < 16; ++i) tmp[i] = f2b(hp[i]);
        *(uint4*)(a_sm + SW32(row, 8 + seg * 2))     = *(uint4*)(tmp);
        *(uint4*)(a_sm + SW32(row, 8 + seg * 2 + 1)) = *(uint4*)(tmp + 8);
    }
    if (tid < 32) keep2[0][tid] = done[b0 + tid] ? 0.0f : 1.0f;

    // gate-0, jc-0 weight base for this wave's columns
    const u16* wbase = Wcat + (size_t)(jg * 64 + l16) * KP_ + quad * 8;
    const bf16x8 zero8 = {0, 0, 0, 0, 0, 0, 0, 0};

    for (int t = 0; t < T_; ++t) {
        __syncthreads();                       // barrier 1: A(t), keep(t) visible
        const bool last = (t == T_ - 1);

        // prefetch x(t+1) / done(t+1) into regs
        uint4 xn = make_uint4(0u, 0u, 0u, 0u);
        int dn_next = 0;
        if (!last && tid < 256) {
            const int row = tid >> 3, ch = tid & 7;
            xn = *(const uint4*)(xpad + ((size_t)(t + 1) * B_ + b0 + row) * 64 + ch * 8);
        }
        if (!last && tid < 32) dn_next = done[(size_t)(t + 1) * B_ + b0 + tid];

        // A-frag preload (regs) + keep masking
        const float kpA = keep2[t & 1][mf * 16 + l16];
        float kpc[4];
        #pragma unroll
        for (int r = 0; r < 4; ++r) kpc[r] = keep2[t & 1][mf * 16 + quad * 4 + r];
        bf16x8 A[10];
        #pragma unroll
        for (int kt = 0; kt < 10; ++kt)
            A[kt] = *(const bf16x8*)(a_sm + SW32(mf * 16 + l16, kt * 4 + quad));
        if (kpA == 0.0f) {
            #pragma unroll
            for (int kt = 2; kt < 10; ++kt) A[kt] = zero8;   // zero h-part only
        }
        __syncthreads();                       // barrier 2: a_sm free for t+1

        // write x(t+1) and keep(t+1)
        if (!last && tid < 256) {
            const int row = tid >> 3, ch = tid & 7;
            *(uint4*)(a_sm + SW32(row, ch)) = xn;
        }
        if (!last && tid < 32) keep2[(t + 1) & 1][tid] = dn_next ? 0.0f : 1.0f;

        // ---- MFMA: 4 jc x 10 kt x 4 gates, ring-4 B prefetch over 40 slots ----
        bf16x8 Bq[4][4];
        #pragma unroll
        for (int s = 0; s < 4; ++s)
            #pragma unroll
            for (int g = 0; g < 4; ++g)
                Bq[s][g] = *(const bf16x8*)(wbase + (size_t)g * 256 * KP_ + s * 32);

        #pragma unroll
        for (int jc = 0; jc < 4; ++jc) {
            f32x4 ai = {0,0,0,0}, af = {0,0,0,0}, ag = {0,0,0,0}, ao = {0,0,0,0};
            #pragma unroll
            for (int kt = 0; kt < 10; ++kt) {
                const int s  = jc * 10 + kt;
                const int rs = s & 3;
                const bf16x8 bI = Bq[rs][0], bF = Bq[rs][1],
                             bG = Bq[rs][2], bO = Bq[rs][3];
                if (s + 4 < 40) {
                    const int s2 = s + 4, jc2 = s2 / 10, kt2 = s2 % 10;
                    #pragma unroll
                    for (int g = 0; g < 4; ++g)
                        Bq[rs][g] = *(const bf16x8*)(wbase + (size_t)g * 256 * KP_
                                                     + (size_t)jc2 * 16 * KP_ + kt2 * 32);
                }
                ai = __builtin_amdgcn_mfma_f32_16x16x32_bf16(A[kt], bI, ai, 0, 0, 0);
                af = __builtin_amdgcn_mfma_f32_16x16x32_bf16(A[kt], bF, af, 0, 0, 0);
                ag = __builtin_amdgcn_mfma_f32_16x16x32_bf16(A[kt], bG, ag, 0, 0, 0);
                ao = __builtin_amdgcn_mfma_f32_16x16x32_bf16(A[kt], bO, ao, 0, 0, 0);
            }
            // ---- epilogue for this jc: all in registers ----
            #pragma unroll
            for (int r = 0; r < 4; ++r) {
                const float gi = ai[r] + bias[jc][0];
                const float gf = af[r] + bias[jc][1];
                const float gg = ag[r] + bias[jc][2];
                const float go = ao[r] + bias[jc][3];
                const float cold = c_reg[jc][r] * kpc[r];
                const float cn = sigm(gf) * cold + sigm(gi) * tanh_fast(gg);
                c_reg[jc][r] = cn;
                const u16 hb = f2b(sigm(go) * tanh_fast(cn));
                const int row_l = mf * 16 + quad * 4 + r;
                const int col   = jg * 64 + jc * 16 + l16;
                a_sm[SW32(row_l, 8 + (col >> 3)) + (col & 7)] = hb;   // A(t+1) h-part
                hs_out[((size_t)t * B_ + b0 + row_l) * H_ + col] = hb;
            }
        }
    }
}

// ---------------------------------------------------------------------------
// Fused LN -> MLP -> heads, all GEMMs on MFMA. 32 rows per block, 4 waves.
// (unchanged from round 4)
// ---------------------------------------------------------------------------
__global__ __launch_bounds__(256, 2) void mlp_mfma(
    const u16*  __restrict__ hs,    // [nrows][256] bf16
    float*      __restrict__ out,   // [nrows][14]
    const float* __restrict__ lng, const float* __restrict__ lnb,
    const u16*  __restrict__ W1T, const float* __restrict__ b1,
    const u16*  __restrict__ W2T, const float* __restrict__ b2,
    const u16*  __restrict__ WhT,
    const float* __restrict__ bm, const float* __restrict__ bs)
{
    __shared__ u16   ybf[32][264];
    __shared__ u16   y1bf[32][520];
    __shared__ float ls[32][12];

    const int tid  = threadIdx.x;
    const int lane = tid & 63;
    const int wave = tid >> 6;
    const int quad = lane >> 4, l16 = lane & 15;
    const int row0 = blockIdx.x * 32;

    // ---- LayerNorm ----
    {
        const float4 gv = *(const float4*)(lng + lane * 4);
        const float4 bv = *(const float4*)(lnb + lane * 4);
        for (int rr = 0; rr < 8; ++rr) {
            const int r = wave * 8 + rr;
            const ushort4 hv = *(const ushort4*)(hs + (size_t)(row0 + r) * H_ + lane * 4);
            const float v0 = b2f(hv.x), v1 = b2f(hv.y), v2 = b2f(hv.z), v3 = b2f(hv.w);
            float s  = v0 + v1 + v2 + v3;
            float ss = v0 * v0 + v1 * v1 + v2 * v2 + v3 * v3;
            #pragma unroll
            for (int off = 32; off > 0; off >>= 1) {
                s  += __shfl_down(s,  off);
                ss += __shfl_down(ss, off);
            }
            s = __shfl(s, 0); ss = __shfl(ss, 0);
            const float mu   = s * (1.0f / 256.0f);
            const float rstd = rsqrtf(ss * (1.0f / 256.0f) - mu * mu + 1e-5f);
            ushort4 o;
            o.x = f2b((v0 - mu) * rstd * gv.x + bv.x);
            o.y = f2b((v1 - mu) * rstd * gv.y + bv.y);
            o.z = f2b((v2 - mu) * rstd * gv.z + bv.z);
            o.w = f2b((v3 - mu) * rstd * gv.w + bv.w);
            *(ushort4*)(&ybf[r][lane * 4]) = o;
        }
    }
    __syncthreads();

    // ---- Layer 1 with weight prefetch ----
    {
        f32x4 acc[2][8];
        #pragma unroll
        for (int i = 0; i < 2; ++i)
            #pragma unroll
            for (int j = 0; j < 8; ++j) acc[i][j] = (f32x4){0,0,0,0};
        const u16* wpB = W1T + (size_t)(wave * 128 + l16) * 256 + quad * 8;
        bf16x8 bwc[8], bwn[8];
        #pragma unroll
        for (int j = 0; j < 8; ++j) bwc[j] = *(const bf16x8*)(wpB + (size_t)j * 16 * 256);
        #pragma unroll
        for (int kt = 0; kt < 8; ++kt) {
            const int k0 = kt * 32;
            if (kt < 7) {
                #pragma unroll
                for (int j = 0; j < 8; ++j)
                    bwn[j] = *(const bf16x8*)(wpB + (size_t)j * 16 * 256 + k0 + 32);
            }
            const bf16x8 af0 = *(const bf16x8*)(&ybf[l16][k0 + quad * 8]);
            const bf16x8 af1 = *(const bf16x8*)(&ybf[16 + l16][k0 + quad * 8]);
            #pragma unroll
            for (int j = 0; j < 8; ++j) {
                acc[0][j] = __builtin_amdgcn_mfma_f32_16x16x32_bf16(af0, bwc[j], acc[0][j], 0, 0, 0);
                acc[1][j] = __builtin_amdgcn_mfma_f32_16x16x32_bf16(af1, bwc[j], acc[1][j], 0, 0, 0);
            }
            #pragma unroll
            for (int j = 0; j < 8; ++j) bwc[j] = bwn[j];
        }
        #pragma unroll
        for (int j = 0; j < 8; ++j) {
            const int n = wave * 128 + j * 16 + l16;
            const float bb = b1[n];
            #pragma unroll
            for (int i = 0; i < 2; ++i)
                #pragma unroll
                for (int r = 0; r < 4; ++r)
                    y1bf[i * 16 + quad * 4 + r][n] = f2b(elu(acc[i][j][r] + bb));
        }
    }
    __syncthreads();

    // ---- Layer 2 with weight prefetch ----
    {
        f32x4 acc[2][4];
        #pragma unroll
        for (int i = 0; i < 2; ++i)
            #pragma unroll
            for (int j = 0; j < 4; ++j) acc[i][j] = (f32x4){0,0,0,0};
        const u16* wpB = W2T + (size_t)(wave * 64 + l16) * 512 + quad * 8;
        bf16x8 bwc[4], bwn[4];
        #pragma unroll
        for (int j = 0; j < 4; ++j) bwc[j] = *(const bf16x8*)(wpB + (size_t)j * 16 * 512);
        #pragma unroll
        for (int kt = 0; kt < 16; ++kt) {
            const int k0 = kt * 32;
            if (kt < 15) {
                #pragma unroll
                for (int j = 0; j < 4; ++j)
                    bwn[j] = *(const bf16x8*)(wpB + (size_t)j * 16 * 512 + k0 + 32);
            }
            const bf16x8 af0 = *(const bf16x8*)(&y1bf[l16][k0 + quad * 8]);
            const bf16x8 af1 = *(const bf16x8*)(&y1bf[16 + l16][k0 + quad * 8]);
            #pragma unroll
            for (int j = 0; j < 4; ++j) {
                acc[0][j] = __builtin_amdgcn_mfma_f32_16x16x32_bf16(af0, bwc[j], acc[0][j], 0, 0, 0);
                acc[1][j] = __builtin_amdgcn_mfma_f32_16x16x32_bf16(af1, bwc[j], acc[1][j], 0, 0, 0);
            }
            #pragma unroll
            for (int j = 0; j < 4; ++j) bwc[j] = bwn[j];
        }
        #pragma unroll
        for (int j = 0; j < 4; ++j) {
            const int n = wave * 64 + j * 16 + l16;
            const float bb = b2[n];
            #pragma unroll
            for (int i = 0; i < 2; ++i)
                #pragma unroll
                for (int r = 0; r < 4; ++r)
                    ybf[i * 16 + quad * 4 + r][n] = f2b(elu(acc[i][j][r] + bb));
        }
    }
    __syncthreads();

    // ---- Heads ----
    if (wave < 2) {
        f32x4 a0 = {0,0,0,0}, a1 = {0,0,0,0};
        const u16* wp = WhT + (size_t)(wave * 16 + l16) * 256 + quad * 8;
        for (int kt = 0; kt < 8; ++kt) {
            const int k0 = kt * 32;
            const bf16x8 af0 = *(const bf16x8*)(&ybf[l16][k0 + quad * 8]);
            const bf16x8 af1 = *(const bf16x8*)(&ybf[16 + l16][k0 + quad * 8]);
            const bf16x8 bw  = *(const bf16x8*)(wp + k0);
            a0 = __builtin_amdgcn_mfma_f32_16x16x32_bf16(af0, bw, a0, 0, 0, 0);
            a1 = __builtin_amdgcn_mfma_f32_16x16x32_bf16(af1, bw, a1, 0, 0, 0);
        }
        if (l16 < 12) {
            f32x4 aa[2] = {a0, a1};
            if (wave == 0) {
                const float bb = bm[l16];
                #pragma unroll
                for (int i = 0; i < 2; ++i)
                    #pragma unroll
                    for (int r = 0; r < 4; ++r) {
                        const int m = i * 16 + quad * 4 + r;
                        out[(size_t)(row0 + m) * 14 + l16] = aa[i][r] + bb;
                    }
            } else {
                const float bb = bs[l16];
                #pragma unroll
                for (int i = 0; i < 2; ++i)
                    #pragma unroll
                    for (int r = 0; r < 4; ++r) {
                        const int m = i * 16 + quad * 4 + r;
                        ls[m][l16] = fminf(fmaxf(aa[i][r] + bb, -5.0f), 2.0f);
                    }
            }
        }
    }
    __syncthreads();
    if (tid < 32) {
        float s = 0.0f;
        #pragma unroll
        for (int q = 0; q < 12; ++q) s += ls[tid][q];
        const float LOG2PI = 1.8378770664093453f;
        out[(size_t)(row0 + tid) * 14 + 12] = -s - 6.0f * LOG2PI;
        out[(size_t)(row0 + tid) * 14 + 13] =  s + 6.0f + 6.0f * LOG2PI;
    }
}

// ---------------------------------------------------------------------------
extern "C" void kernel_launch(void* const* d_in, const int* in_sizes, int n_in,
                              void* d_out, int out_size, void* d_ws, size_t ws_size,
                              hipStream_t stream) {
    (void)in_sizes; (void)n_in; (void)out_size; (void)ws_size;
    const float* x    = (const float*)d_in[0];
    const int*   done = (const int*)  d_in[1];
    const float* h0   = (const float*)d_in[2];
    const float* c0   = (const float*)d_in[3];
    const float* W_ih = (const float*)d_in[4];
    const float* W_hh = (const float*)d_in[5];
    const float* b_ih = (const float*)d_in[6];
    const float* b_hh = (const float*)d_in[7];
    const float* lng  = (const float*)d_in[8];
    const float* lnb  = (const float*)d_in[9];
    const float* W1   = (const float*)d_in[10];
    const float* b1   = (const float*)d_in[11];
    const float* W2   = (const float*)d_in[12];
    const float* b2   = (const float*)d_in[13];
    const float* Wm   = (const float*)d_in[14];
    const float* bm   = (const float*)d_in[15];
    const float* Ws   = (const float*)d_in[16];
    const float* bs   = (const float*)d_in[17];
    float* out = (float*)d_out;

    // workspace carve (~84 MB; ws_size >= 135 MB confirmed)
    unsigned char* p = (unsigned char*)d_ws;
    u16* hs    = (u16*)p;              p += (size_t)T_ * BH_ * 2;
    u16* xpad  = (u16*)p;              p += (size_t)T_ * B_ * 64 * 2;
    u16* Wcat  = (u16*)p;              p += (size_t)1024 * KP_ * 2;
    u16* W1T   = (u16*)p;              p += (size_t)M1_ * H_ * 2;
    u16* W2T   = (u16*)p;              p += (size_t)M2_ * M1_ * 2;
    u16* WhT   = (u16*)p;              p += (size_t)32 * H_ * 2;

    prep_xpad<<<(T_ * B_ * 64) / 256, 256, 0, stream>>>(x, xpad);
    prep_wcat<<<1024, KP_, 0, stream>>>(W_ih, W_hh, Wcat);
    prep_w1t<<<M1_, 256, 0, stream>>>(W1, W1T);
    prep_w2t<<<M2_, 512, 0, stream>>>(W2, W2T);
    prep_wht<<<32, 256, 0, stream>>>(Wm, Ws, WhT);

    lstm_scan_rows<<<64, 512, 0, stream>>>(
        xpad, done, hs, h0, c0, Wcat, b_ih, b_hh);

    mlp_mfma<<<(T_ * B_) / 32, 256, 0, stream>>>(
        hs, out, lng, lnb, W1T, b1, W2T, b2, WhT, bm, bs);
}

// Round 6
// 3408.493 us; speedup vs baseline: 1.0137x; 1.0137x over previous
//
#include <hip/hip_runtime.h>
#include <hip/hip_bf16.h>
#include <math.h>

#define T_   64
#define B_   2048
#define OBS_ 48
#define H_   256
#define M1_  512
#define M2_  256
#define A_   12
#define BH_  (B_ * H_)
#define KP_  320   // padded K: 64 (x, padded from 48) + 256 (h)

typedef unsigned short u16;
typedef unsigned int   u32;
typedef __attribute__((ext_vector_type(8))) short bf16x8;
typedef __attribute__((ext_vector_type(4))) float f32x4;

static __device__ __forceinline__ u16 f2b(float f) {
    __hip_bfloat16 h = __float2bfloat16(f);
    return *reinterpret_cast<u16*>(&h);
}
static __device__ __forceinline__ float b2f(u16 u) {
    union { unsigned u32v; float f; } v; v.u32v = ((unsigned)u) << 16; return v.f;
}
static __device__ __forceinline__ float sigm(float x) {
    return 1.0f / (1.0f + __expf(-x));
}
static __device__ __forceinline__ float tanh_fast(float x) {
    x = fminf(fmaxf(x, -15.0f), 15.0f);
    float e = __expf(2.0f * x);
    return (e - 1.0f) / (e + 1.0f);
}
static __device__ __forceinline__ float elu(float x) {
    return x > 0.0f ? x : (__expf(x) - 1.0f);
}

// ---------------------------------------------------------------------------
// prep_xpad: vectorized x -> bf16 [T*B][64] (K padded 48->64 with zeros)
// grid 4096 x 256; each thread converts 8 elements.
// ---------------------------------------------------------------------------
__global__ void prep_xpad(const float* __restrict__ x, u16* __restrict__ xpad) {
    const int gid = blockIdx.x * 256 + threadIdx.x;   // T*B*8 threads
    const int r = gid >> 3, k0 = (gid & 7) * 8;
    u16 tmp[8];
    if (k0 < OBS_) {
        const float4 f0 = *(const float4*)(x + (size_t)r * OBS_ + k0);
        const float4 f1 = *(const float4*)(x + (size_t)r * OBS_ + k0 + 4);
        tmp[0] = f2b(f0.x); tmp[1] = f2b(f0.y); tmp[2] = f2b(f0.z); tmp[3] = f2b(f0.w);
        tmp[4] = f2b(f1.x); tmp[5] = f2b(f1.y); tmp[6] = f2b(f1.z); tmp[7] = f2b(f1.w);
    } else {
        #pragma unroll
        for (int i = 0; i < 8; ++i) tmp[i] = 0;
    }
    *(uint4*)(xpad + (size_t)gid * 8) = *(uint4*)tmp;
}

// ---------------------------------------------------------------------------
// merged weight prep: Wcat / W1T / W2T / WhT in one dispatch (grid 1824 x 256)
// ---------------------------------------------------------------------------
__global__ void prep_weights(const float* __restrict__ W_ih, const float* __restrict__ W_hh,
                             const float* __restrict__ W1,  const float* __restrict__ W2,
                             const float* __restrict__ Wm,  const float* __restrict__ Ws,
                             u16* __restrict__ Wcat, u16* __restrict__ W1T,
                             u16* __restrict__ W2T,  u16* __restrict__ WhT) {
    const int b = blockIdx.x, tid = threadIdx.x;
    if (b < 1024) {
        for (int k = tid; k < KP_; k += 256) {
            float v;
            if (k < OBS_)    v = W_ih[b * OBS_ + k];
            else if (k < 64) v = 0.0f;
            else             v = W_hh[b * H_ + (k - 64)];
            Wcat[b * KP_ + k] = f2b(v);
        }
    } else if (b < 1536) {
        const int n = b - 1024;                       // W1T [512][256]
        W1T[n * 256 + tid] = f2b(W1[tid * M1_ + n]);
    } else if (b < 1792) {
        const int n = b - 1536;                       // W2T [256][512]
        W2T[n * 512 + tid]       = f2b(W2[tid * M2_ + n]);
        W2T[n * 512 + tid + 256] = f2b(W2[(tid + 256) * M2_ + n]);
    } else {
        const int n = b - 1792;                       // WhT [32][256]
        float v = 0.0f;
        if (n < 12)                 v = Wm[tid * A_ + n];
        else if (n >= 16 && n < 28) v = Ws[tid * A_ + (n - 16)];
        WhT[n * 256 + tid] = f2b(v);
    }
}

// ---------------------------------------------------------------------------
// Single-dispatch row-partitioned LSTM scan. 32 blocks x 512 thr; block owns
// 64 batch rows x ALL 1024 gate cols x ALL 64 steps -> zero inter-block deps.
// - 4 blocks/XCD x 640 KB Wcat stream = 2.56 MB < 4 MB L2 (fixes round-5 thrash)
// - 8 waves = (row-half 0..1) x (hcol-group 0..3); each wave: 4 passes of
//   16 h-cols x 4 gates -> gate fusion + c update fully in registers.
// - h state: 32 KB swizzled LDS (single buffer, 2 barriers/step, reg stash).
// - x fragments read directly from global xpad (no LDS staging).
// - B: flattened (pass,kt) stream with ring-4 register prefetch from L2.
// - hs_out written as coalesced dwordx4, deferred one step.
// ---------------------------------------------------------------------------
#define SWH(row, c) ((size_t)(row) * 256 + (size_t)(((c) ^ ((row) & 7)) << 3))

__global__ __launch_bounds__(512, 2) void lstm_scan64(
    const u16*  __restrict__ xpad,   // [T][B][64]
    const int*  __restrict__ done,   // [T][B]
    u16*        __restrict__ hs_out, // [T][B][256]  (hs_out[t] = h after step t)
    const float* __restrict__ h0,
    const float* __restrict__ c0,
    const u16*  __restrict__ Wcat,   // [1024][320]
    const float* __restrict__ b_ih,
    const float* __restrict__ b_hh)
{
    __shared__ u16   h_sm[64 * 256];   // 32 KB, XOR-swizzled 16B chunks
    __shared__ float keep_sm[64];

    const int tid  = threadIdx.x;
    const int lane = tid & 63;
    const int wave = tid >> 6;        // 0..7
    const int mh   = wave & 1;        // 32-row half
    const int hg   = wave >> 1;       // hcol group (64 h-cols)
    const int quad = lane >> 4, l16 = lane & 15;
    const int b0 = blockIdx.x * 64;
    const bf16x8 zero8 = {0, 0, 0, 0, 0, 0, 0, 0};

    // ---- bias regs [pass][gate] ----
    float bias[4][4];
    #pragma unroll
    for (int p = 0; p < 4; ++p) {
        const int col = hg * 64 + p * 16 + l16;
        #pragma unroll
        for (int g = 0; g < 4; ++g)
            bias[p][g] = b_ih[g * 256 + col] + b_hh[g * 256 + col];
    }

    // ---- persistent c regs [pass][mi][r] ----
    float c_reg[4][2][4];
    #pragma unroll
    for (int p = 0; p < 4; ++p)
        #pragma unroll
        for (int mi = 0; mi < 2; ++mi)
            #pragma unroll
            for (int r = 0; r < 4; ++r)
                c_reg[p][mi][r] = c0[(size_t)(b0 + mh * 32 + mi * 16 + quad * 4 + r) * H_
                                     + hg * 64 + p * 16 + l16];

    // ---- stage H(0) = h0 (bf16) + keep(0) ----
    {
        const int row = tid >> 3, seg = tid & 7;
        const float* hp = h0 + (size_t)(b0 + row) * H_ + seg * 32;
        #pragma unroll
        for (int i = 0; i < 4; ++i) {
            u16 t8[8];
            #pragma unroll
            for (int j = 0; j < 8; ++j) t8[j] = f2b(hp[i * 8 + j]);
            *(uint4*)(h_sm + SWH(row, seg * 4 + i)) = *(uint4*)t8;
        }
    }
    if (tid < 64) keep_sm[tid] = done[b0 + tid] ? 0.0f : 1.0f;

    const u16* wb = Wcat + (size_t)(hg * 64 + l16) * KP_ + quad * 8;

    for (int t = 0; t < T_; ++t) {
        __syncthreads();   // barrier 1: h_sm = H(t), keep_sm = keep(t)

        // ---- x fragments for step t (global, held in regs) ----
        bf16x8 XF[2][2];
        #pragma unroll
        for (int mi = 0; mi < 2; ++mi)
            #pragma unroll
            for (int kx = 0; kx < 2; ++kx)
                XF[mi][kx] = *(const bf16x8*)(
                    xpad + ((size_t)t * B_ + b0 + mh * 32 + mi * 16 + l16) * 64
                         + kx * 32 + quad * 8);

        // ---- done(t+1) prefetch ----
        int dn = 0;
        if (t < T_ - 1 && tid < 64) dn = done[(size_t)(t + 1) * B_ + b0 + tid];

        // ---- deferred hs_out[t-1] = H(t): coalesced copy from LDS ----
        if (t > 0) {
            const int row = tid >> 3, seg = tid & 7;
            u16* dst = hs_out + ((size_t)(t - 1) * B_ + b0 + row) * H_ + seg * 32;
            #pragma unroll
            for (int i = 0; i < 4; ++i)
                *(uint4*)(dst + i * 8) = *(const uint4*)(h_sm + SWH(row, seg * 4 + i));
        }

        // ---- keep regs ----
        const float kpA0 = keep_sm[mh * 32 + l16];
        const float kpA1 = keep_sm[mh * 32 + 16 + l16];
        float kpc[2][4];
        #pragma unroll
        for (int mi = 0; mi < 2; ++mi)
            #pragma unroll
            for (int r = 0; r < 4; ++r)
                kpc[mi][r] = keep_sm[mh * 32 + mi * 16 + quad * 4 + r];

        // ---- ring-4 B prefetch over flattened 40-slot (pass,kt) stream ----
        bf16x8 Bq[4][4];
        #pragma unroll
        for (int s = 0; s < 4; ++s)
            #pragma unroll
            for (int g = 0; g < 4; ++g)
                Bq[s][g] = *(const bf16x8*)(wb + ((size_t)g * 256) * KP_ + s * 32);

        u32 hst[16];   // packed h stash: [pass][mi][r-pair]

        #pragma unroll
        for (int p = 0; p < 4; ++p) {
            f32x4 acc[2][4];
            #pragma unroll
            for (int mi = 0; mi < 2; ++mi)
                #pragma unroll
                for (int g = 0; g < 4; ++g) acc[mi][g] = (f32x4){0, 0, 0, 0};

            #pragma unroll
            for (int kt = 0; kt < 10; ++kt) {
                const int s = p * 10 + kt, rs = s & 3;
                bf16x8 a0, a1;
                if (kt < 2) {
                    a0 = XF[0][kt]; a1 = XF[1][kt];
                } else {
                    a0 = *(const bf16x8*)(h_sm + SWH(mh * 32 + l16,      (kt - 2) * 4 + quad));
                    a1 = *(const bf16x8*)(h_sm + SWH(mh * 32 + 16 + l16, (kt - 2) * 4 + quad));
                    if (kpA0 == 0.0f) a0 = zero8;
                    if (kpA1 == 0.0f) a1 = zero8;
                }
                const bf16x8 bI = Bq[rs][0], bF = Bq[rs][1], bG = Bq[rs][2], bO = Bq[rs][3];
                if (s + 4 < 40) {
                    const int s2 = s + 4, p2 = s2 / 10, kt2 = s2 % 10;
                    #pragma unroll
                    for (int g = 0; g < 4; ++g)
                        Bq[rs][g] = *(const bf16x8*)(
                            wb + ((size_t)g * 256 + p2 * 16) * KP_ + kt2 * 32);
                }
                acc[0][0] = __builtin_amdgcn_mfma_f32_16x16x32_bf16(a0, bI, acc[0][0], 0, 0, 0);
                acc[0][1] = __builtin_amdgcn_mfma_f32_16x16x32_bf16(a0, bF, acc[0][1], 0, 0, 0);
                acc[0][2] = __builtin_amdgcn_mfma_f32_16x16x32_bf16(a0, bG, acc[0][2], 0, 0, 0);
                acc[0][3] = __builtin_amdgcn_mfma_f32_16x16x32_bf16(a0, bO, acc[0][3], 0, 0, 0);
                acc[1][0] = __builtin_amdgcn_mfma_f32_16x16x32_bf16(a1, bI, acc[1][0], 0, 0, 0);
                acc[1][1] = __builtin_amdgcn_mfma_f32_16x16x32_bf16(a1, bF, acc[1][1], 0, 0, 0);
                acc[1][2] = __builtin_amdgcn_mfma_f32_16x16x32_bf16(a1, bG, acc[1][2], 0, 0, 0);
                acc[1][3] = __builtin_amdgcn_mfma_f32_16x16x32_bf16(a1, bO, acc[1][3], 0, 0, 0);
            }

            // ---- epilogue pass p: gates -> c (regs), h -> packed stash ----
            #pragma unroll
            for (int mi = 0; mi < 2; ++mi)
                #pragma unroll
                for (int rr = 0; rr < 2; ++rr) {
                    u32 pk = 0;
                    #pragma unroll
                    for (int h2 = 0; h2 < 2; ++h2) {
                        const int r = rr * 2 + h2;
                        const float gi = acc[mi][0][r] + bias[p][0];
                        const float gf = acc[mi][1][r] + bias[p][1];
                        const float gg = acc[mi][2][r] + bias[p][2];
                        const float go = acc[mi][3][r] + bias[p][3];
                        const float cold = c_reg[p][mi][r] * kpc[mi][r];
                        const float cn = sigm(gf) * cold + sigm(gi) * tanh_fast(gg);
                        c_reg[p][mi][r] = cn;
                        pk |= ((u32)f2b(sigm(go) * tanh_fast(cn))) << (h2 * 16);
                    }
                    hst[p * 4 + mi * 2 + rr] = pk;
                }
        }

        __syncthreads();   // barrier 2: all reads of H(t) complete

        // ---- write H(t+1) into h_sm; update keep ----
        #pragma unroll
        for (int p = 0; p < 4; ++p)
            #pragma unroll
            for (int mi = 0; mi < 2; ++mi)
                #pragma unroll
                for (int rr = 0; rr < 2; ++rr) {
                    const u32 pk = hst[p * 4 + mi * 2 + rr];
                    #pragma unroll
                    for (int h2 = 0; h2 < 2; ++h2) {
                        const int r = rr * 2 + h2;
                        const int row_l = mh * 32 + mi * 16 + quad * 4 + r;
                        const int col   = hg * 64 + p * 16 + l16;
                        h_sm[SWH(row_l, col >> 3) + (col & 7)] = (u16)(pk >> (h2 * 16));
                    }
                }
        if (t < T_ - 1 && tid < 64) keep_sm[tid] = dn ? 0.0f : 1.0f;
    }

    __syncthreads();
    // final: hs_out[T-1] = H(T)
    {
        const int row = tid >> 3, seg = tid & 7;
        u16* dst = hs_out + ((size_t)(T_ - 1) * B_ + b0 + row) * H_ + seg * 32;
        #pragma unroll
        for (int i = 0; i < 4; ++i)
            *(uint4*)(dst + i * 8) = *(const uint4*)(h_sm + SWH(row, seg * 4 + i));
    }
}

// ---------------------------------------------------------------------------
// Fused LN -> MLP -> heads (unchanged from round 4)
// ---------------------------------------------------------------------------
__global__ __launch_bounds__(256, 2) void mlp_mfma(
    const u16*  __restrict__ hs,    // [nrows][256] bf16
    float*      __restrict__ out,   // [nrows][14]
    const float* __restrict__ lng, const float* __restrict__ lnb,
    const u16*  __restrict__ W1T, const float* __restrict__ b1,
    const u16*  __restrict__ W2T, const float* __restrict__ b2,
    const u16*  __restrict__ WhT,
    const float* __restrict__ bm, const float* __restrict__ bs)
{
    __shared__ u16   ybf[32][264];
    __shared__ u16   y1bf[32][520];
    __shared__ float ls[32][12];

    const int tid  = threadIdx.x;
    const int lane = tid & 63;
    const int wave = tid >> 6;
    const int quad = lane >> 4, l16 = lane & 15;
    const int row0 = blockIdx.x * 32;

    // ---- LayerNorm ----
    {
        const float4 gv = *(const float4*)(lng + lane * 4);
        const float4 bv = *(const float4*)(lnb + lane * 4);
        for (int rr = 0; rr < 8; ++rr) {
            const int r = wave * 8 + rr;
            const ushort4 hv = *(const ushort4*)(hs + (size_t)(row0 + r) * H_ + lane * 4);
            const float v0 = b2f(hv.x), v1 = b2f(hv.y), v2 = b2f(hv.z), v3 = b2f(hv.w);
            float s  = v0 + v1 + v2 + v3;
            float ss = v0 * v0 + v1 * v1 + v2 * v2 + v3 * v3;
            #pragma unroll
            for (int off = 32; off > 0; off >>= 1) {
                s  += __shfl_down(s,  off);
                ss += __shfl_down(ss, off);
            }
            s = __shfl(s, 0); ss = __shfl(ss, 0);
            const float mu   = s * (1.0f / 256.0f);
            const float rstd = rsqrtf(ss * (1.0f / 256.0f) - mu * mu + 1e-5f);
            ushort4 o;
            o.x = f2b((v0 - mu) * rstd * gv.x + bv.x);
            o.y = f2b((v1 - mu) * rstd * gv.y + bv.y);
            o.z = f2b((v2 - mu) * rstd * gv.z + bv.z);
            o.w = f2b((v3 - mu) * rstd * gv.w + bv.w);
            *(ushort4*)(&ybf[r][lane * 4]) = o;
        }
    }
    __syncthreads();

    // ---- Layer 1 with weight prefetch ----
    {
        f32x4 acc[2][8];
        #pragma unroll
        for (int i = 0; i < 2; ++i)
            #pragma unroll
            for (int j = 0; j < 8; ++j) acc[i][j] = (f32x4){0,0,0,0};
        const u16* wpB = W1T + (size_t)(wave * 128 + l16) * 256 + quad * 8;
        bf16x8 bwc[8], bwn[8];
        #pragma unroll
        for (int j = 0; j < 8; ++j) bwc[j] = *(const bf16x8*)(wpB + (size_t)j * 16 * 256);
        #pragma unroll
        for (int kt = 0; kt < 8; ++kt) {
            const int k0 = kt * 32;
            if (kt < 7) {
                #pragma unroll
                for (int j = 0; j < 8; ++j)
                    bwn[j] = *(const bf16x8*)(wpB + (size_t)j * 16 * 256 + k0 + 32);
            }
            const bf16x8 af0 = *(const bf16x8*)(&ybf[l16][k0 + quad * 8]);
            const bf16x8 af1 = *(const bf16x8*)(&ybf[16 + l16][k0 + quad * 8]);
            #pragma unroll
            for (int j = 0; j < 8; ++j) {
                acc[0][j] = __builtin_amdgcn_mfma_f32_16x16x32_bf16(af0, bwc[j], acc[0][j], 0, 0, 0);
                acc[1][j] = __builtin_amdgcn_mfma_f32_16x16x32_bf16(af1, bwc[j], acc[1][j], 0, 0, 0);
            }
            #pragma unroll
            for (int j = 0; j < 8; ++j) bwc[j] = bwn[j];
        }
        #pragma unroll
        for (int j = 0; j < 8; ++j) {
            const int n = wave * 128 + j * 16 + l16;
            const float bb = b1[n];
            #pragma unroll
            for (int i = 0; i < 2; ++i)
                #pragma unroll
                for (int r = 0; r < 4; ++r)
                    y1bf[i * 16 + quad * 4 + r][n] = f2b(elu(acc[i][j][r] + bb));
        }
    }
    __syncthreads();

    // ---- Layer 2 with weight prefetch ----
    {
        f32x4 acc[2][4];
        #pragma unroll
        for (int i = 0; i < 2; ++i)
            #pragma unroll
            for (int j = 0; j < 4; ++j) acc[i][j] = (f32x4){0,0,0,0};
        const u16* wpB = W2T + (size_t)(wave * 64 + l16) * 512 + quad * 8;
        bf16x8 bwc[4], bwn[4];
        #pragma unroll
        for (int j = 0; j < 4; ++j) bwc[j] = *(const bf16x8*)(wpB + (size_t)j * 16 * 512);
        #pragma unroll
        for (int kt = 0; kt < 16; ++kt) {
            const int k0 = kt * 32;
            if (kt < 15) {
                #pragma unroll
                for (int j = 0; j < 4; ++j)
                    bwn[j] = *(const bf16x8*)(wpB + (size_t)j * 16 * 512 + k0 + 32);
            }
            const bf16x8 af0 = *(const bf16x8*)(&y1bf[l16][k0 + quad * 8]);
            const bf16x8 af1 = *(const bf16x8*)(&y1bf[16 + l16][k0 + quad * 8]);
            #pragma unroll
            for (int j = 0; j < 4; ++j) {
                acc[0][j] = __builtin_amdgcn_mfma_f32_16x16x32_bf16(af0, bwc[j], acc[0][j], 0, 0, 0);
                acc[1][j] = __builtin_amdgcn_mfma_f32_16x16x32_bf16(af1, bwc[j], acc[1][j], 0, 0, 0);
            }
            #pragma unroll
            for (int j = 0; j < 4; ++j) bwc[j] = bwn[j];
        }
        #pragma unroll
        for (int j = 0; j < 4; ++j) {
            const int n = wave * 64 + j * 16 + l16;
            const float bb = b2[n];
            #pragma unroll
            for (int i = 0; i < 2; ++i)
                #pragma unroll
                for (int r = 0; r < 4; ++r)
                    ybf[i * 16 + quad * 4 + r][n] = f2b(elu(acc[i][j][r] + bb));
        }
    }
    __syncthreads();

    // ---- Heads ----
    if (wave < 2) {
        f32x4 a0 = {0,0,0,0}, a1 = {0,0,0,0};
        const u16* wp = WhT + (size_t)(wave * 16 + l16) * 256 + quad * 8;
        for (int kt = 0; kt < 8; ++kt) {
            const int k0 = kt * 32;
            const bf16x8 af0 = *(const bf16x8*)(&ybf[l16][k0 + quad * 8]);
            const bf16x8 af1 = *(const bf16x8*)(&ybf[16 + l16][k0 + quad * 8]);
            const bf16x8 bw  = *(const bf16x8*)(wp + k0);
            a0 = __builtin_amdgcn_mfma_f32_16x16x32_bf16(af0, bw, a0, 0, 0, 0);
            a1 = __builtin_amdgcn_mfma_f32_16x16x32_bf16(af1, bw, a1, 0, 0, 0);
        }
        if (l16 < 12) {
            f32x4 aa[2] = {a0, a1};
            if (wave == 0) {
                const float bb = bm[l16];
                #pragma unroll
                for (int i = 0; i < 2; ++i)
                    #pragma unroll
                    for (int r = 0; r < 4; ++r) {
                        const int m = i * 16 + quad * 4 + r;
                        out[(size_t)(row0 + m) * 14 + l16] = aa[i][r] + bb;
                    }
            } else {
                const float bb = bs[l16];
                #pragma unroll
                for (int i = 0; i < 2; ++i)
                    #pragma unroll
                    for (int r = 0; r < 4; ++r) {
                        const int m = i * 16 + quad * 4 + r;
                        ls[m][l16] = fminf(fmaxf(aa[i][r] + bb, -5.0f), 2.0f);
                    }
            }
        }
    }
    __syncthreads();
    if (tid < 32) {
        float s = 0.0f;
        #pragma unroll
        for (int q = 0; q < 12; ++q) s += ls[tid][q];
        const float LOG2PI = 1.8378770664093453f;
        out[(size_t)(row0 + tid) * 14 + 12] = -s - 6.0f * LOG2PI;
        out[(size_t)(row0 + tid) * 14 + 13] =  s + 6.0f + 6.0f * LOG2PI;
    }
}

// ---------------------------------------------------------------------------
extern "C" void kernel_launch(void* const* d_in, const int* in_sizes, int n_in,
                              void* d_out, int out_size, void* d_ws, size_t ws_size,
                              hipStream_t stream) {
    (void)in_sizes; (void)n_in; (void)out_size; (void)ws_size;
    const float* x    = (const float*)d_in[0];
    const int*   done = (const int*)  d_in[1];
    const float* h0   = (const float*)d_in[2];
    const float* c0   = (const float*)d_in[3];
    const float* W_ih = (const float*)d_in[4];
    const float* W_hh = (const float*)d_in[5];
    const float* b_ih = (const float*)d_in[6];
    const float* b_hh = (const float*)d_in[7];
    const float* lng  = (const float*)d_in[8];
    const float* lnb  = (const float*)d_in[9];
    const float* W1   = (const float*)d_in[10];
    const float* b1   = (const float*)d_in[11];
    const float* W2   = (const float*)d_in[12];
    const float* b2   = (const float*)d_in[13];
    const float* Wm   = (const float*)d_in[14];
    const float* bm   = (const float*)d_in[15];
    const float* Ws   = (const float*)d_in[16];
    const float* bs   = (const float*)d_in[17];
    float* out = (float*)d_out;

    // workspace carve (~81 MB; ws_size >= 135 MB confirmed)
    unsigned char* p = (unsigned char*)d_ws;
    u16* hs    = (u16*)p;              p += (size_t)T_ * BH_ * 2;
    u16* xpad  = (u16*)p;              p += (size_t)T_ * B_ * 64 * 2;
    u16* Wcat  = (u16*)p;              p += (size_t)1024 * KP_ * 2;
    u16* W1T   = (u16*)p;              p += (size_t)M1_ * H_ * 2;
    u16* W2T   = (u16*)p;              p += (size_t)M2_ * M1_ * 2;
    u16* WhT   = (u16*)p;              p += (size_t)32 * H_ * 2;

    prep_xpad<<<(T_ * B_ * 8) / 256, 256, 0, stream>>>(x, xpad);
    prep_weights<<<1824, 256, 0, stream>>>(W_ih, W_hh, W1, W2, Wm, Ws,
                                           Wcat, W1T, W2T, WhT);

    lstm_scan64<<<32, 512, 0, stream>>>(xpad, done, hs, h0, c0, Wcat, b_ih, b_hh);

    mlp_mfma<<<(T_ * B_) / 32, 256, 0, stream>>>(
        hs, out, lng, lnb, W1T, b1, W2T, b2, WhT, bm, bs);
}

// Round 7
// 963.122 us; speedup vs baseline: 3.5876x; 3.5390x over previous
//
#include <hip/hip_runtime.h>
#include <hip/hip_bf16.h>
#include <math.h>

#define T_   64
#define B_   2048
#define OBS_ 48
#define H_   256
#define M1_  512
#define M2_  256
#define A_   12
#define BH_  (B_ * H_)
#define KP_  320   // padded K for scan: 64 (x, padded from 48) + 256 (h)

typedef unsigned short u16;
typedef __attribute__((ext_vector_type(8))) short bf16x8;
typedef __attribute__((ext_vector_type(4))) float f32x4;

static __device__ __forceinline__ u16 f2b(float f) {
    __hip_bfloat16 h = __float2bfloat16(f);
    return *reinterpret_cast<u16*>(&h);
}
static __device__ __forceinline__ float b2f(u16 u) {
    union { unsigned u32v; float f; } v; v.u32v = ((unsigned)u) << 16; return v.f;
}
static __device__ __forceinline__ float sigm(float x) {
    return 1.0f / (1.0f + __expf(-x));
}
static __device__ __forceinline__ float tanh_fast(float x) {
    x = fminf(fmaxf(x, -15.0f), 15.0f);
    float e = __expf(2.0f * x);
    return (e - 1.0f) / (e + 1.0f);
}
static __device__ __forceinline__ float elu(float x) {
    return x > 0.0f ? x : (__expf(x) - 1.0f);
}

// ---------------------------------------------------------------------------
// Pre-pass kernels
// ---------------------------------------------------------------------------
__global__ void prep_xpad(const float* __restrict__ x, u16* __restrict__ xpad) {
    const int gid = blockIdx.x * 256 + threadIdx.x;   // T*B*8 threads
    const int r = gid >> 3, k0 = (gid & 7) * 8;
    u16 tmp[8];
    if (k0 < OBS_) {
        const float4 f0 = *(const float4*)(x + (size_t)r * OBS_ + k0);
        const float4 f1 = *(const float4*)(x + (size_t)r * OBS_ + k0 + 4);
        tmp[0] = f2b(f0.x); tmp[1] = f2b(f0.y); tmp[2] = f2b(f0.z); tmp[3] = f2b(f0.w);
        tmp[4] = f2b(f1.x); tmp[5] = f2b(f1.y); tmp[6] = f2b(f1.z); tmp[7] = f2b(f1.w);
    } else {
        #pragma unroll
        for (int i = 0; i < 8; ++i) tmp[i] = 0;
    }
    *(uint4*)(xpad + (size_t)gid * 8) = *(uint4*)tmp;
}

__global__ void prep_weights(const float* __restrict__ W_ih, const float* __restrict__ W_hh,
                             const float* __restrict__ W1,  const float* __restrict__ W2,
                             const float* __restrict__ Wm,  const float* __restrict__ Ws,
                             u16* __restrict__ Wcat, u16* __restrict__ W1T,
                             u16* __restrict__ W2T,  u16* __restrict__ WhT) {
    const int b = blockIdx.x, tid = threadIdx.x;
    if (b < 1024) {
        for (int k = tid; k < KP_; k += 256) {
            float v;
            if (k < OBS_)    v = W_ih[b * OBS_ + k];
            else if (k < 64) v = 0.0f;
            else             v = W_hh[b * H_ + (k - 64)];
            Wcat[b * KP_ + k] = f2b(v);
        }
    } else if (b < 1536) {
        const int n = b - 1024;                       // W1T [512][256]
        W1T[n * 256 + tid] = f2b(W1[tid * M1_ + n]);
    } else if (b < 1792) {
        const int n = b - 1536;                       // W2T [256][512]
        W2T[n * 512 + tid]       = f2b(W2[tid * M2_ + n]);
        W2T[n * 512 + tid + 256] = f2b(W2[(tid + 256) * M2_ + n]);
    } else {
        const int n = b - 1792;                       // WhT [32][256]
        float v = 0.0f;
        if (n < 12)                 v = Wm[tid * A_ + n];
        else if (n >= 16 && n < 28) v = Ws[tid * A_ + (n - 16)];
        WhT[n * 256 + tid] = f2b(v);
    }
}

__global__ void init_state2(const float* __restrict__ h0, const float* __restrict__ c0,
                            u16* __restrict__ hs0, float* __restrict__ Cst) {
    const int i = blockIdx.x * 256 + threadIdx.x;
    hs0[i] = f2b(h0[i]);
    Cst[i] = c0[i];
}

// ---------------------------------------------------------------------------
// LSTM step (round-4 kernel, known-good ~11.7 us/step incl. dispatch).
// Grid (32,16): block = 64 b-rows x (4 gates x 16 j), 4 waves of 32x32.
// ---------------------------------------------------------------------------
#define ASM_(row, chunk) (a_sm + (size_t)(row) * 320 + (size_t)(((chunk) ^ ((row) & 7)) << 3))

__global__ __launch_bounds__(256, 2) void lstm_step4(
    const u16*  __restrict__ xpad_t,  // [B][64]
    const int*  __restrict__ done_t,  // [B]
    const u16*  __restrict__ Hin,     // [B][256] bf16
    u16*        __restrict__ Hout,    // [B][256] bf16
    float*      __restrict__ Cst,     // [B][256] fp32, in-place
    const u16*  __restrict__ Wcat,    // [1024][320]
    const float* __restrict__ b_ih,
    const float* __restrict__ b_hh)
{
    __shared__ u16   a_sm[64 * 320];   // 40 KB, XOR-swizzled
    __shared__ float g_sm[64][68];     // 17.4 KB
    __shared__ float keep_sm[64];

    const int tid  = threadIdx.x;
    const int lane = tid & 63;
    const int wave = tid >> 6;
    const int wm = wave & 1, wn = wave >> 1;
    const int quad = lane >> 4, l16 = lane & 15;
    const int b0 = blockIdx.x * 64;
    const int j0 = blockIdx.y * 16;

    // ---- preload B fragments (20 frags = 80 VGPRs; Wcat is L2-resident) ----
    bf16x8 Bf0[10], Bf1[10];
    {
        const u16* wp0 = Wcat + ((size_t)((wn * 2 + 0) * 256 + j0 + l16)) * KP_ + quad * 8;
        const u16* wp1 = Wcat + ((size_t)((wn * 2 + 1) * 256 + j0 + l16)) * KP_ + quad * 8;
        #pragma unroll
        for (int kt = 0; kt < 10; ++kt) {
            Bf0[kt] = *(const bf16x8*)(wp0 + kt * 32);
            Bf1[kt] = *(const bf16x8*)(wp1 + kt * 32);
        }
    }

    // ---- stage A tile: whole K=320 in one shot ----
    if (tid < 64) keep_sm[tid] = done_t[b0 + tid] ? 0.0f : 1.0f;
    {
        const int srow = tid >> 2;     // 0..63
        const int sseg = tid & 3;      // 0..3
        const u16* xrow = xpad_t + (size_t)(b0 + srow) * 64;
        const uint4 xv0 = *(const uint4*)(xrow + sseg * 8);
        const uint4 xv1 = *(const uint4*)(xrow + (sseg + 4) * 8);
        *(uint4*)ASM_(srow, sseg)     = xv0;
        *(uint4*)ASM_(srow, sseg + 4) = xv1;

        const int dn = done_t[b0 + srow];
        const u16* hrow = Hin + (size_t)(b0 + srow) * H_ + sseg * 64;
        #pragma unroll
        for (int i = 0; i < 8; ++i) {
            uint4 hv = *(const uint4*)(hrow + i * 8);
            if (dn) hv = make_uint4(0u, 0u, 0u, 0u);
            *(uint4*)ASM_(srow, 8 + sseg * 8 + i) = hv;
        }
    }
    __syncthreads();

    // ---- 40 MFMA per wave ----
    f32x4 acc00 = {0,0,0,0}, acc01 = {0,0,0,0}, acc10 = {0,0,0,0}, acc11 = {0,0,0,0};
    #pragma unroll
    for (int kt = 0; kt < 10; ++kt) {
        const bf16x8 af0 = *(const bf16x8*)ASM_(wm * 32 +  0 + l16, kt * 4 + quad);
        const bf16x8 af1 = *(const bf16x8*)ASM_(wm * 32 + 16 + l16, kt * 4 + quad);
        acc00 = __builtin_amdgcn_mfma_f32_16x16x32_bf16(af0, Bf0[kt], acc00, 0, 0, 0);
        acc01 = __builtin_amdgcn_mfma_f32_16x16x32_bf16(af0, Bf1[kt], acc01, 0, 0, 0);
        acc10 = __builtin_amdgcn_mfma_f32_16x16x32_bf16(af1, Bf0[kt], acc10, 0, 0, 0);
        acc11 = __builtin_amdgcn_mfma_f32_16x16x32_bf16(af1, Bf1[kt], acc11, 0, 0, 0);
    }

    // ---- accs -> LDS for cross-wave gate fusion ----
    #pragma unroll
    for (int r = 0; r < 4; ++r) {
        g_sm[wm * 32 +  0 + quad * 4 + r][wn * 32 +  0 + l16] = acc00[r];
        g_sm[wm * 32 +  0 + quad * 4 + r][wn * 32 + 16 + l16] = acc01[r];
        g_sm[wm * 32 + 16 + quad * 4 + r][wn * 32 +  0 + l16] = acc10[r];
        g_sm[wm * 32 + 16 + quad * 4 + r][wn * 32 + 16 + l16] = acc11[r];
    }
    __syncthreads();

    // ---- epilogue: gates -> c (fp32 global), h -> Hout (bf16) ----
    const int jj = tid & 15, bq = tid >> 4;
    const int jg = j0 + jj;
    const float bi_b = b_ih[jg]       + b_hh[jg];
    const float bf_b = b_ih[256 + jg] + b_hh[256 + jg];
    const float bg_b = b_ih[512 + jg] + b_hh[512 + jg];
    const float bo_b = b_ih[768 + jg] + b_hh[768 + jg];
    #pragma unroll
    for (int r = 0; r < 4; ++r) {
        const int b = bq * 4 + r;
        const float gi = g_sm[b][jj]      + bi_b;
        const float gf = g_sm[b][16 + jj] + bf_b;
        const float gg = g_sm[b][32 + jj] + bg_b;
        const float go = g_sm[b][48 + jj] + bo_b;
        const size_t idx = (size_t)(b0 + b) * H_ + jg;
        const float cold = Cst[idx] * keep_sm[b];
        const float cn = sigm(gf) * cold + sigm(gi) * tanh_fast(gg);
        Cst[idx] = cn;
        Hout[idx] = f2b(sigm(go) * tanh_fast(cn));
    }
}

// ---------------------------------------------------------------------------
// MLP v2: 64 rows/block, 512 threads (8 waves), two-phase y1 (K-partial L2
// accumulation in registers) -> exactly 64 KB LDS, 2 blocks/CU.
// Halves per-row weight traffic vs 32-row version.
// ---------------------------------------------------------------------------
#define SY(row, col) ((size_t)(row) * 256 + ((((col) >> 3) ^ ((row) & 7)) << 3) + ((col) & 7))

__global__ __launch_bounds__(512, 4) void mlp_mfma64(
    const u16*  __restrict__ hs,    // [nrows][256] bf16
    float*      __restrict__ out,   // [nrows][14]
    const float* __restrict__ lng, const float* __restrict__ lnb,
    const u16*  __restrict__ W1T, const float* __restrict__ b1,
    const u16*  __restrict__ W2T, const float* __restrict__ b2,
    const u16*  __restrict__ WhT,
    const float* __restrict__ bm, const float* __restrict__ bs)
{
    __shared__ u16 ybf[64 * 256];   // 32 KB swizzled: LN output, later y2
    __shared__ u16 yh [64 * 256];   // 32 KB swizzled: y1 column-half; later ls overlay

    const int tid  = threadIdx.x;
    const int lane = tid & 63;
    const int wave = tid >> 6;        // 0..7
    const int quad = lane >> 4, l16 = lane & 15;
    const int row0 = blockIdx.x * 64;

    // ---- LayerNorm: wave w -> rows w*8..w*8+7; lane holds 4 cols ----
    {
        const float4 gv = *(const float4*)(lng + lane * 4);
        const float4 bv = *(const float4*)(lnb + lane * 4);
        #pragma unroll
        for (int rr = 0; rr < 8; ++rr) {
            const int r = wave * 8 + rr;
            const ushort4 hv = *(const ushort4*)(hs + (size_t)(row0 + r) * H_ + lane * 4);
            const float v0 = b2f(hv.x), v1 = b2f(hv.y), v2 = b2f(hv.z), v3 = b2f(hv.w);
            float s  = v0 + v1 + v2 + v3;
            float ss = v0 * v0 + v1 * v1 + v2 * v2 + v3 * v3;
            #pragma unroll
            for (int off = 32; off > 0; off >>= 1) {
                s  += __shfl_down(s,  off);
                ss += __shfl_down(ss, off);
            }
            s = __shfl(s, 0); ss = __shfl(ss, 0);
            const float mu   = s * (1.0f / 256.0f);
            const float rstd = rsqrtf(ss * (1.0f / 256.0f) - mu * mu + 1e-5f);
            ushort4 o;
            o.x = f2b((v0 - mu) * rstd * gv.x + bv.x);
            o.y = f2b((v1 - mu) * rstd * gv.y + bv.y);
            o.z = f2b((v2 - mu) * rstd * gv.z + bv.z);
            o.w = f2b((v3 - mu) * rstd * gv.w + bv.w);
            *(ushort4*)(ybf + SY(r, lane * 4)) = o;
        }
    }
    __syncthreads();

    // ---- L2 partial accumulators: live across both phases ----
    f32x4 acc2[4][2];
    #pragma unroll
    for (int m = 0; m < 4; ++m)
        #pragma unroll
        for (int j = 0; j < 2; ++j) acc2[m][j] = (f32x4){0,0,0,0};

    #pragma unroll
    for (int ph = 0; ph < 2; ++ph) {
        // ---- L1 phase: y1 cols [ph*256, ph*256+256); wave n-slice 32 cols ----
        {
            f32x4 acc[4][2];
            #pragma unroll
            for (int m = 0; m < 4; ++m)
                #pragma unroll
                for (int j = 0; j < 2; ++j) acc[m][j] = (f32x4){0,0,0,0};
            const int n0 = ph * 256 + wave * 32;
            const u16* wp0 = W1T + (size_t)(n0 + l16) * 256 + quad * 8;
            const u16* wp1 = W1T + (size_t)(n0 + 16 + l16) * 256 + quad * 8;
            #pragma unroll
            for (int kt = 0; kt < 8; ++kt) {
                const int k0 = kt * 32;
                const bf16x8 bw0 = *(const bf16x8*)(wp0 + k0);
                const bf16x8 bw1 = *(const bf16x8*)(wp1 + k0);
                #pragma unroll
                for (int m = 0; m < 4; ++m) {
                    const bf16x8 af = *(const bf16x8*)(ybf + SY(m * 16 + l16, k0 + quad * 8));
                    acc[m][0] = __builtin_amdgcn_mfma_f32_16x16x32_bf16(af, bw0, acc[m][0], 0, 0, 0);
                    acc[m][1] = __builtin_amdgcn_mfma_f32_16x16x32_bf16(af, bw1, acc[m][1], 0, 0, 0);
                }
            }
            const float bb0 = b1[n0 + l16], bb1 = b1[n0 + 16 + l16];
            __syncthreads();   // yh free (prev phase consumed / first use)
            #pragma unroll
            for (int m = 0; m < 4; ++m)
                #pragma unroll
                for (int r = 0; r < 4; ++r) {
                    const int row = m * 16 + quad * 4 + r;
                    yh[SY(row, wave * 32 + l16)]      = f2b(elu(acc[m][0][r] + bb0));
                    yh[SY(row, wave * 32 + 16 + l16)] = f2b(elu(acc[m][1][r] + bb1));
                }
        }
        __syncthreads();

        // ---- L2 partial: K in [ph*256, ph*256+256); wave n-slice 32 cols ----
        {
            const int n0 = wave * 32;
            const u16* wp0 = W2T + (size_t)(n0 + l16) * 512 + ph * 256 + quad * 8;
            const u16* wp1 = W2T + (size_t)(n0 + 16 + l16) * 512 + ph * 256 + quad * 8;
            #pragma unroll
            for (int kt = 0; kt < 8; ++kt) {
                const int k0 = kt * 32;
                const bf16x8 bw0 = *(const bf16x8*)(wp0 + k0);
                const bf16x8 bw1 = *(const bf16x8*)(wp1 + k0);
                #pragma unroll
                for (int m = 0; m < 4; ++m) {
                    const bf16x8 af = *(const bf16x8*)(yh + SY(m * 16 + l16, k0 + quad * 8));
                    acc2[m][0] = __builtin_amdgcn_mfma_f32_16x16x32_bf16(af, bw0, acc2[m][0], 0, 0, 0);
                    acc2[m][1] = __builtin_amdgcn_mfma_f32_16x16x32_bf16(af, bw1, acc2[m][1], 0, 0, 0);
                }
            }
        }
        __syncthreads();
    }

    // ---- y2 = elu(acc2 + b2) -> ybf (LN data fully consumed) ----
    {
        const float bb0 = b2[wave * 32 + l16], bb1 = b2[wave * 32 + 16 + l16];
        #pragma unroll
        for (int m = 0; m < 4; ++m)
            #pragma unroll
            for (int r = 0; r < 4; ++r) {
                const int row = m * 16 + quad * 4 + r;
                ybf[SY(row, wave * 32 + l16)]      = f2b(elu(acc2[m][0][r] + bb0));
                ybf[SY(row, wave * 32 + 16 + l16)] = f2b(elu(acc2[m][1][r] + bb1));
            }
    }
    __syncthreads();

    // ---- Heads: waves 0..3 -> m-frag = wave; j=0 mean, j=1 logstd ----
    float* lsf = (float*)yh;   // overlay: [64][16] floats (yh free)
    if (wave < 4) {
        f32x4 a0 = {0,0,0,0}, a1 = {0,0,0,0};
        const u16* wp0 = WhT + (size_t)l16 * 256 + quad * 8;          // mean rows 0..15
        const u16* wp1 = WhT + (size_t)(16 + l16) * 256 + quad * 8;   // logstd rows 16..31
        #pragma unroll
        for (int kt = 0; kt < 8; ++kt) {
            const int k0 = kt * 32;
            const bf16x8 af  = *(const bf16x8*)(ybf + SY(wave * 16 + l16, k0 + quad * 8));
            const bf16x8 bw0 = *(const bf16x8*)(wp0 + k0);
            const bf16x8 bw1 = *(const bf16x8*)(wp1 + k0);
            a0 = __builtin_amdgcn_mfma_f32_16x16x32_bf16(af, bw0, a0, 0, 0, 0);
            a1 = __builtin_amdgcn_mfma_f32_16x16x32_bf16(af, bw1, a1, 0, 0, 0);
        }
        if (l16 < 12) {
            const float bbm = bm[l16], bbs = bs[l16];
            #pragma unroll
            for (int r = 0; r < 4; ++r) {
                const int row = wave * 16 + quad * 4 + r;
                out[(size_t)(row0 + row) * 14 + l16] = a0[r] + bbm;
                lsf[row * 16 + l16] = fminf(fmaxf(a1[r] + bbs, -5.0f), 2.0f);
            }
        }
    }
    __syncthreads();
    if (tid < 64) {
        float s = 0.0f;
        #pragma unroll
        for (int q = 0; q < 12; ++q) s += lsf[tid * 16 + q];
        const float LOG2PI = 1.8378770664093453f;
        out[(size_t)(row0 + tid) * 14 + 12] = -s - 6.0f * LOG2PI;
        out[(size_t)(row0 + tid) * 14 + 13] =  s + 6.0f + 6.0f * LOG2PI;
    }
}

// ---------------------------------------------------------------------------
extern "C" void kernel_launch(void* const* d_in, const int* in_sizes, int n_in,
                              void* d_out, int out_size, void* d_ws, size_t ws_size,
                              hipStream_t stream) {
    (void)in_sizes; (void)n_in; (void)out_size; (void)ws_size;
    const float* x    = (const float*)d_in[0];
    const int*   done = (const int*)  d_in[1];
    const float* h0   = (const float*)d_in[2];
    const float* c0   = (const float*)d_in[3];
    const float* W_ih = (const float*)d_in[4];
    const float* W_hh = (const float*)d_in[5];
    const float* b_ih = (const float*)d_in[6];
    const float* b_hh = (const float*)d_in[7];
    const float* lng  = (const float*)d_in[8];
    const float* lnb  = (const float*)d_in[9];
    const float* W1   = (const float*)d_in[10];
    const float* b1   = (const float*)d_in[11];
    const float* W2   = (const float*)d_in[12];
    const float* b2   = (const float*)d_in[13];
    const float* Wm   = (const float*)d_in[14];
    const float* bm   = (const float*)d_in[15];
    const float* Ws   = (const float*)d_in[16];
    const float* bs   = (const float*)d_in[17];
    float* out = (float*)d_out;

    // workspace carve (~37 MB; ws_size >= 135 MB confirmed)
    unsigned char* p = (unsigned char*)d_ws;
    u16* hs    = (u16*)p;              p += (size_t)(T_ + 1) * BH_ * 2;
    u16* xpad  = (u16*)p;              p += (size_t)T_ * B_ * 64 * 2;
    u16* Wcat  = (u16*)p;              p += (size_t)1024 * KP_ * 2;
    u16* W1T   = (u16*)p;              p += (size_t)M1_ * H_ * 2;
    u16* W2T   = (u16*)p;              p += (size_t)M2_ * M1_ * 2;
    u16* WhT   = (u16*)p;              p += (size_t)32 * H_ * 2;
    float* Cst = (float*)p;            p += (size_t)BH_ * 4;

    prep_xpad<<<(T_ * B_ * 8) / 256, 256, 0, stream>>>(x, xpad);
    prep_weights<<<1824, 256, 0, stream>>>(W_ih, W_hh, W1, W2, Wm, Ws,
                                           Wcat, W1T, W2T, WhT);
    init_state2<<<BH_ / 256, 256, 0, stream>>>(h0, c0, hs, Cst);

    for (int t = 0; t < T_; ++t) {
        lstm_step4<<<dim3(32, 16), 256, 0, stream>>>(
            xpad + (size_t)t * B_ * 64,
            done + (size_t)t * B_,
            hs + (size_t)t * BH_,
            hs + (size_t)(t + 1) * BH_,
            Cst, Wcat, b_ih, b_hh);
    }

    mlp_mfma64<<<(T_ * B_) / 64, 512, 0, stream>>>(
        hs + BH_, out, lng, lnb, W1T, b1, W2T, b2, WhT, bm, bs);
}